// Round 19
// baseline (28645.532 us; speedup 1.0000x reference)
//
#include <hip/hip_runtime.h>

typedef unsigned short u16;
typedef __attribute__((ext_vector_type(4))) float f32x4;
typedef __attribute__((ext_vector_type(8))) short short8;

#define NUM_T 256
#define BATCH 1024
#define DIM 64
#define HID 768
#define PHID 512
#define PREP 10
#define GIN 640
#define COVSZ 32
#define COVH 128
#define DT_ 0.05f
#define VEPS 1e-6f
#define NTH 512
#define NWAVE 8
#define NWG 256
#define GQ 4
#define GROUPS 64

#define LHB 776
#define LPH 520
#define LPF 132
#define LPB 136
#define LZH 776
#define LGI 648

#define MFMA_ __builtin_amdgcn_mfma_f32_16x16x32_bf16

struct Params {
  const float *X, *M; const int *obs; const float *cov;
  const float *bxz, *bxn, *bp1, *bp2, *bc1, *bc2, *bih, *bhh, *wprep, *bprep;
  const float *Wc1, *Wc2;
  const u16 *Wxz, *Wxn, *Whz, *Whn, *Wp1, *Wp2, *Wih, *Whh;
  float *out_h; float *partials; u16 *exch; unsigned *cnt;
};

__device__ __forceinline__ u16 f2bf(float f){
  unsigned u = __builtin_bit_cast(unsigned, f);
  u = (u + 0x7FFFu + ((u >> 16) & 1u)) >> 16;
  return (u16)u;
}
__device__ __forceinline__ float bf2f(u16 h){
  unsigned u = ((unsigned)h) << 16;
  return __builtin_bit_cast(float, u);
}
__device__ __forceinline__ float sigm(float x){ return 1.0f/(1.0f + __expf(-x)); }
__device__ __forceinline__ float tanh_f(float x){
  float t = __expf(-2.0f*fabsf(x));
  float r = (1.0f - t)/(1.0f + t);
  return x >= 0.0f ? r : -r;
}

struct Smem {
  u16   h_b[16*LHB];
  u16   z_b[16*LHB];
  float p_f[16*LPF];
  u16   p_b[16*LPB];
  union {
    u16 zh[16*LZH];
    u16 gi[16*LGI];
    u16 ph1[16*LPH];
  } u;
  int om[2][16];
  float red[NWAVE];
};

// Depth-4 NT-slot paced GEMM (r19): named sets A..D (static indices), issue
// chunk kk+4 after MFMAs of chunk kk, s_barrier per chunk. Per-accumulator
// MFMA k-order sequential (= r12/r17/r18) -> bit-identical.
template<int NKC, int NT>
__device__ __forceinline__ void dotP(const u16* __restrict__ A, int lda,
    const u16* __restrict__ W2, int tile0, f32x4* acc,
    int c, int g, int lane, int w)
{
  static_assert((NKC & 3) == 0, "NKC % 4");
  const u16* a = A + c*lda + g*8;
  const short8* base[NT];
  #pragma unroll
  for (int j = 0; j < NT; ++j)
    base[j] = (const short8*)(W2 + ((size_t)(tile0 + w + 8*j)*NKC)*512) + lane;
  short8 sA[NT], sB[NT], sC[NT], sD[NT];
  #pragma unroll
  for (int j = 0; j < NT; ++j) sA[j] = base[j][0];
  #pragma unroll
  for (int j = 0; j < NT; ++j) sB[j] = base[j][64];
  #pragma unroll
  for (int j = 0; j < NT; ++j) sC[j] = base[j][128];
  #pragma unroll
  for (int j = 0; j < NT; ++j) sD[j] = base[j][192];
  __builtin_amdgcn_s_barrier();
  #pragma unroll 1
  for (int kp = 0; kp < NKC/4; ++kp){
    int kk = 4*kp;
    {
      short8 av = *(const short8*)(a + 32*kk);
      #pragma unroll
      for (int j = 0; j < NT; ++j) acc[j] = MFMA_(av, sA[j], acc[j], 0, 0, 0);
      if (kk + 4 < NKC){
        #pragma unroll
        for (int j = 0; j < NT; ++j) sA[j] = base[j][64*(kk + 4)];
      }
      __builtin_amdgcn_s_barrier();
    }
    {
      short8 av = *(const short8*)(a + 32*(kk + 1));
      #pragma unroll
      for (int j = 0; j < NT; ++j) acc[j] = MFMA_(av, sB[j], acc[j], 0, 0, 0);
      if (kk + 5 < NKC){
        #pragma unroll
        for (int j = 0; j < NT; ++j) sB[j] = base[j][64*(kk + 5)];
      }
      __builtin_amdgcn_s_barrier();
    }
    {
      short8 av = *(const short8*)(a + 32*(kk + 2));
      #pragma unroll
      for (int j = 0; j < NT; ++j) acc[j] = MFMA_(av, sC[j], acc[j], 0, 0, 0);
      if (kk + 6 < NKC){
        #pragma unroll
        for (int j = 0; j < NT; ++j) sC[j] = base[j][64*(kk + 6)];
      }
      __builtin_amdgcn_s_barrier();
    }
    {
      short8 av = *(const short8*)(a + 32*(kk + 3));
      #pragma unroll
      for (int j = 0; j < NT; ++j) acc[j] = MFMA_(av, sD[j], acc[j], 0, 0, 0);
      if (kk + 7 < NKC){
        #pragma unroll
        for (int j = 0; j < NT; ++j) sD[j] = base[j][64*(kk + 7)];
      }
      __builtin_amdgcn_s_barrier();
    }
  }
}

// Depth-4 guarded 2-slot GEMM (tiles t0 always, t1 if v1).
template<int NKC>
__device__ __forceinline__ void dotPG(const u16* __restrict__ A, int lda,
    const u16* __restrict__ W2, int t0, int t1, bool v1, f32x4* acc,
    int c, int g, int lane)
{
  static_assert((NKC & 3) == 0, "NKC % 4");
  const u16* a = A + c*lda + g*8;
  const short8* b0 = (const short8*)(W2 + ((size_t)t0*NKC)*512) + lane;
  const short8* b1 = (const short8*)(W2 + ((size_t)t1*NKC)*512) + lane;
  short8 A0, B0, C0, D0, A1, B1, C1, D1;
  A0 = b0[0]; B0 = b0[64]; C0 = b0[128]; D0 = b0[192];
  if (v1){ A1 = b1[0]; B1 = b1[64]; C1 = b1[128]; D1 = b1[192]; }
  __builtin_amdgcn_s_barrier();
  #pragma unroll 1
  for (int kp = 0; kp < NKC/4; ++kp){
    int kk = 4*kp;
    {
      short8 av = *(const short8*)(a + 32*kk);
      acc[0] = MFMA_(av, A0, acc[0], 0, 0, 0);
      if (v1) acc[1] = MFMA_(av, A1, acc[1], 0, 0, 0);
      if (kk + 4 < NKC){ A0 = b0[64*(kk + 4)]; if (v1) A1 = b1[64*(kk + 4)]; }
      __builtin_amdgcn_s_barrier();
    }
    {
      short8 av = *(const short8*)(a + 32*(kk + 1));
      acc[0] = MFMA_(av, B0, acc[0], 0, 0, 0);
      if (v1) acc[1] = MFMA_(av, B1, acc[1], 0, 0, 0);
      if (kk + 5 < NKC){ B0 = b0[64*(kk + 5)]; if (v1) B1 = b1[64*(kk + 5)]; }
      __builtin_amdgcn_s_barrier();
    }
    {
      short8 av = *(const short8*)(a + 32*(kk + 2));
      acc[0] = MFMA_(av, C0, acc[0], 0, 0, 0);
      if (v1) acc[1] = MFMA_(av, C1, acc[1], 0, 0, 0);
      if (kk + 6 < NKC){ C0 = b0[64*(kk + 6)]; if (v1) C1 = b1[64*(kk + 6)]; }
      __builtin_amdgcn_s_barrier();
    }
    {
      short8 av = *(const short8*)(a + 32*(kk + 3));
      acc[0] = MFMA_(av, D0, acc[0], 0, 0, 0);
      if (v1) acc[1] = MFMA_(av, D1, acc[1], 0, 0, 0);
      if (kk + 7 < NKC){ D0 = b0[64*(kk + 7)]; if (v1) D1 = b1[64*(kk + 7)]; }
      __builtin_amdgcn_s_barrier();
    }
  }
}

// Depth-4 guarded 3-gate streamer (tiles {t0, 48+t0, 96+t0}), barriers
// unconditional, s_barrier per chunk.
template<int NKC>
__device__ __forceinline__ void dot3PG(const u16* __restrict__ A, int lda,
    const u16* __restrict__ W2, int t0, bool act, f32x4* acc, int c, int g, int lane)
{
  static_assert((NKC & 3) == 0, "NKC % 4");
  const u16* a = A + c*lda + g*8;
  const short8* base[3];
  #pragma unroll
  for (int j = 0; j < 3; ++j)
    base[j] = (const short8*)(W2 + ((size_t)(t0 + 48*j)*NKC)*512) + lane;
  short8 sA[3], sB[3], sC[3], sD[3];
  if (act){
    #pragma unroll
    for (int j = 0; j < 3; ++j) sA[j] = base[j][0];
    #pragma unroll
    for (int j = 0; j < 3; ++j) sB[j] = base[j][64];
    #pragma unroll
    for (int j = 0; j < 3; ++j) sC[j] = base[j][128];
    #pragma unroll
    for (int j = 0; j < 3; ++j) sD[j] = base[j][192];
  }
  __builtin_amdgcn_s_barrier();
  #pragma unroll 1
  for (int kp = 0; kp < NKC/4; ++kp){
    int kk = 4*kp;
    if (act){
      short8 av = *(const short8*)(a + 32*kk);
      #pragma unroll
      for (int j = 0; j < 3; ++j) acc[j] = MFMA_(av, sA[j], acc[j], 0, 0, 0);
      if (kk + 4 < NKC){
        #pragma unroll
        for (int j = 0; j < 3; ++j) sA[j] = base[j][64*(kk + 4)];
      }
    }
    __builtin_amdgcn_s_barrier();
    if (act){
      short8 av = *(const short8*)(a + 32*(kk + 1));
      #pragma unroll
      for (int j = 0; j < 3; ++j) acc[j] = MFMA_(av, sB[j], acc[j], 0, 0, 0);
      if (kk + 5 < NKC){
        #pragma unroll
        for (int j = 0; j < 3; ++j) sB[j] = base[j][64*(kk + 5)];
      }
    }
    __builtin_amdgcn_s_barrier();
    if (act){
      short8 av = *(const short8*)(a + 32*(kk + 2));
      #pragma unroll
      for (int j = 0; j < 3; ++j) acc[j] = MFMA_(av, sC[j], acc[j], 0, 0, 0);
      if (kk + 6 < NKC){
        #pragma unroll
        for (int j = 0; j < 3; ++j) sC[j] = base[j][64*(kk + 6)];
      }
    }
    __builtin_amdgcn_s_barrier();
    if (act){
      short8 av = *(const short8*)(a + 32*(kk + 3));
      #pragma unroll
      for (int j = 0; j < 3; ++j) acc[j] = MFMA_(av, sD[j], acc[j], 0, 0, 0);
      if (kk + 7 < NKC){
        #pragma unroll
        for (int j = 0; j < 3; ++j) sD[j] = base[j][64*(kk + 7)];
      }
    }
    __builtin_amdgcn_s_barrier();
  }
}

// Replicated pm2 (8 tiles, wave w owns tile w), NKC=16 (r12-verified).
__device__ __forceinline__ void dotPB16(const u16* __restrict__ A, int lda,
    const u16* __restrict__ W2, f32x4* acc, int c, int g, int lane, int w)
{
  const u16* a = A + c*lda + g*8;
  const short8* base = (const short8*)(W2 + ((size_t)w*16)*512) + lane;
  short8 ldA[4], ldB[4];
  #pragma unroll
  for (int m = 0; m < 4; ++m) ldA[m] = base[64*m];
  #pragma unroll
  for (int m = 0; m < 4; ++m) ldB[m] = base[64*(4 + m)];
  __builtin_amdgcn_s_barrier();
  #pragma unroll
  for (int m = 0; m < 4; ++m){
    short8 av = *(const short8*)(a + 32*m);
    acc[0] = MFMA_(av, ldA[m], acc[0], 0, 0, 0);
  }
  #pragma unroll
  for (int m = 0; m < 4; ++m) ldA[m] = base[64*(8 + m)];
  __builtin_amdgcn_s_barrier();
  #pragma unroll
  for (int m = 0; m < 4; ++m){
    short8 av = *(const short8*)(a + 32*(4 + m));
    acc[0] = MFMA_(av, ldB[m], acc[0], 0, 0, 0);
  }
  #pragma unroll
  for (int m = 0; m < 4; ++m) ldB[m] = base[64*(12 + m)];
  __builtin_amdgcn_s_barrier();
  #pragma unroll
  for (int m = 0; m < 4; ++m){
    short8 av = *(const short8*)(a + 32*(8 + m));
    acc[0] = MFMA_(av, ldA[m], acc[0], 0, 0, 0);
  }
  __builtin_amdgcn_s_barrier();
  #pragma unroll
  for (int m = 0; m < 4; ++m){
    short8 av = *(const short8*)(a + 32*(12 + m));
    acc[0] = MFMA_(av, ldB[m], acc[0], 0, 0, 0);
  }
  __builtin_amdgcn_s_barrier();
}

__global__ __launch_bounds__(NTH)
void nnfo_main(Params pr)
{
  __shared__ Smem sm;
  const int tid  = threadIdx.x;
  const int lane = tid & 63;
  const int w    = tid >> 6;
  const int c = lane & 15;
  const int g = lane >> 4;
  const int b = blockIdx.x;
  const int q    = (b >> 3) & 3;
  const int G    = (b & 7)*8 + (b >> 5);    // group's 4 WGs share an XCD
  const int row0 = G * 16;

  u16* exZH = pr.exch + (size_t)G*32768;
  u16* exH  = exZH + 16*HID;
  u16* exP1 = exH  + 16*HID;
  unsigned* cnt = pr.cnt + G*16;

  unsigned gen = 0;
  auto gsig = [&](){
    __syncthreads();
    if (tid == 0)
      __hip_atomic_fetch_add(cnt, 1u, __ATOMIC_RELEASE, __HIP_MEMORY_SCOPE_AGENT);
    gen += GQ;
  };
  auto gwait = [&](){
    if (tid == 0){
      int spins = 0;
      while (__hip_atomic_load(cnt, __ATOMIC_ACQUIRE, __HIP_MEMORY_SCOPE_AGENT) < gen){
        __builtin_amdgcn_s_sleep(1);
        if (++spins > 8000000) break;
      }
    }
    __syncthreads();
  };
  auto copyLDS = [&](u16* dst, int ldst, const u16* src, int wcols){
    int nb = 16*(wcols >> 3);
    for (int idx = tid; idx < nb; idx += NTH){
      int r = idx/(wcols >> 3), cb = idx - r*(wcols >> 3);
      *(short8*)(dst + r*ldst + cb*8) = *(const short8*)(src + (size_t)r*wcols + cb*8);
    }
    __syncthreads();
  };

  const int  tA0 = q*12 + w;
  const int  tA1 = (w < 4) ? (q*12 + w + 8) : (q*12 + w);
  const bool vA1 = (w < 4);
  const int  tP  = q*8 + w;

  float loss = 0.0f;
  float hreg[2][4];

  // ---- prologue ----
  for (int it = tid; it < 16*COVH; it += NTH){
    int r = it >> 7, j = it & 127;
    float acc = pr.bc1[j];
    const float* cv = pr.cov + (size_t)(row0 + r)*COVSZ;
    const float* wv = pr.Wc1 + (size_t)j*COVSZ;
    for (int k = 0; k < COVSZ; ++k) acc += cv[k]*wv[k];
    sm.p_f[r*LPF + j] = fmaxf(acc, 0.0f);
  }
  __syncthreads();
  for (int it = tid; it < 16*HID; it += NTH){
    int r = it / HID, j = it - r*HID;
    float acc = pr.bc2[j];
    const float* wv = pr.Wc2 + (size_t)j*COVH;
    for (int k = 0; k < COVH; ++k) acc += sm.p_f[r*LPF + k]*wv[k];
    sm.h_b[r*LHB + j] = f2bf(tanh_f(acc));
  }
  #pragma unroll
  for (int s = 0; s < 2; ++s){
    bool act = (s == 0) || vA1;
    int tt = s ? tA1 : tA0;
    int n = tt*16 + c;
    const float* wv = pr.Wc2 + (size_t)n*COVH;
    #pragma unroll
    for (int i = 0; i < 4; ++i){
      int r = g*4 + i;
      float acc = pr.bc2[n];
      for (int k = 0; k < COVH; ++k) acc += sm.p_f[r*LPF + k]*wv[k];
      hreg[s][i] = act ? tanh_f(acc) : 0.0f;
    }
  }
  __syncthreads();

  auto pm1G = [&](){
    f32x4 acc[1] = {};
    dotP<24, 1>(sm.h_b, LHB, pr.Wp1, q*8, acc, c, g, lane, w);
    int n = tP*16 + c;
    float bb = pr.bp1[n];
    #pragma unroll
    for (int i = 0; i < 4; ++i)
      exP1[(size_t)(g*4 + i)*PHID + n] = f2bf(fmaxf(acc[0][i] + bb, 0.0f));
    gsig();
    gwait();
    copyLDS(sm.u.ph1, LPH, exP1, PHID);
  };
  auto pm2R = [&](bool write_pb){
    f32x4 acc[1] = {};
    dotPB16(sm.u.ph1, LPH, pr.Wp2, acc, c, g, lane, w);
    int n = w*16 + c;
    float bb = pr.bp2[n];
    #pragma unroll
    for (int i = 0; i < 4; ++i){
      float v = acc[0][i] + bb;
      sm.p_f[(g*4 + i)*LPF + n] = v;
      if (write_pb) sm.p_b[(g*4 + i)*LPB + n] = f2bf(v);
    }
    __syncthreads();
  };

  pm1G();
  pm2R(true);

  float Xs[2], Ms[2];

  #pragma unroll 1
  for (int t = 0; t < NUM_T; ++t){
    if (tid < 16) sm.om[t & 1][tid] = pr.obs[(size_t)t*BATCH + row0 + tid];
    float Xpre[2];
    #pragma unroll
    for (int q2 = 0; q2 < 2; ++q2){
      int it = tid + q2*NTH;
      int r = it >> 6, d = it & 63;
      Xpre[q2] = pr.X[((size_t)t*BATCH + row0 + r)*DIM + d];
    }

    f32x4 accn[2] = {};   // A2 accumulator, Wxn partial computed during A1's sync window

    // ---- A1: z at owned cols; publish zh; overlap Wxn partial with peer wait ----
    {
      f32x4 accz[2] = {};
      dotPG<4>(sm.p_b, LPB, pr.Wxz, tA0, tA1, vA1, accz, c, g, lane);
      dotPG<24>(sm.h_b, LHB, pr.Whz, tA0, tA1, vA1, accz, c, g, lane);
      #pragma unroll
      for (int s = 0; s < 2; ++s){
        bool act = (s == 0) || vA1;
        if (act){
          int tt = s ? tA1 : tA0;
          int n = tt*16 + c;
          float bb = pr.bxz[n];
          #pragma unroll
          for (int i = 0; i < 4; ++i){
            int r = g*4 + i;
            float z = sigm(accz[s][i] + bb);
            sm.z_b[r*LHB + n] = f2bf(z);
            exZH[(size_t)r*HID + n] = f2bf(z*hreg[s][i]);
          }
        }
      }
      gsig();                                   // publish zh
      dotPG<4>(sm.p_b, LPB, pr.Wxn, tA0, tA1, vA1, accn, c, g, lane);  // overlap
      gwait();
      copyLDS(sm.u.zh, LZH, exZH, HID);
    }
    // ---- A2: h ODE update; publish h ----
    {
      dotPG<24>(sm.u.zh, LZH, pr.Whn, tA0, tA1, vA1, accn, c, g, lane);
      #pragma unroll
      for (int s = 0; s < 2; ++s){
        bool act = (s == 0) || vA1;
        if (act){
          int tt = s ? tA1 : tA0;
          int n = tt*16 + c;
          float bb = pr.bxn[n];
          #pragma unroll
          for (int i = 0; i < 4; ++i){
            int r = g*4 + i;
            float nv = tanh_f(accn[s][i] + bb);
            float z  = bf2f(sm.z_b[r*LHB + n]);
            float h  = hreg[s][i];
            h = h + DT_*(1.0f - z)*(nv - h);
            hreg[s][i] = h;
            exH[(size_t)r*HID + n] = f2bf(h);
          }
        }
      }
      gsig();
      gwait();
      copyLDS(sm.h_b, LHB, exH, HID);
    }

    // ---- B,C ----
    pm1G();
    pm2R(false);

    // ---- D ----
    #pragma unroll
    for (int q2 = 0; q2 < 2; ++q2){
      int it = tid + q2*NTH;
      int r = it >> 6, d = it & 63;
      size_t xoff = ((size_t)t*BATCH + row0 + r)*DIM + d;
      float Xv = Xpre[q2];
      float om = sm.om[t & 1][r] ? 1.0f : 0.0f;
      float Mv = pr.M[xoff] * om;
      Xs[q2] = Xv; Ms[q2] = Mv;
      float mean = sm.p_f[r*LPF + d];
      float var  = sm.p_f[r*LPF + 64 + d];
      float av   = fabsf(var) + VEPS;
      float inv  = rsqrtf(av);
      float errv = (Xv - mean)*inv;
      if (q == 0) loss += 0.5f*(errv*errv + __logf(av))*Mv;
      #pragma unroll
      for (int p = 0; p < PREP; ++p){
        float s = pr.bprep[d*PREP + p]
                + Xv  * pr.wprep[(d*4 + 0)*PREP + p]
                + mean* pr.wprep[(d*4 + 1)*PREP + p]
                + av  * pr.wprep[(d*4 + 2)*PREP + p]
                + errv* pr.wprep[(d*4 + 3)*PREP + p];
        sm.u.gi[r*LGI + d*PREP + p] = f2bf(fmaxf(s, 0.0f)*Mv);
      }
    }
    __syncthreads();

    // ---- E: GRUCell jump at owned cols; publish h ----
    {
      float hn_buf[2][4];
      #pragma unroll 1
      for (int s = 0; s < 2; ++s){
        bool act = (s == 0) || vA1;
        int ht = s ? tA1 : tA0;
        int n = ht*16 + c;
        f32x4 ai[3] = {};
        dot3PG<20>(sm.u.gi, LGI, pr.Wih, ht, act, ai, c, g, lane);
        f32x4 ah[3] = {};
        dot3PG<24>(sm.h_b, LHB, pr.Whh, ht, act, ah, c, g, lane);
        #pragma unroll
        for (int i = 0; i < 4; ++i){
          float ir = ai[0][i] + pr.bih[n];
          float iz = ai[1][i] + pr.bih[HID + n];
          float in = ai[2][i] + pr.bih[2*HID + n];
          float hr = ah[0][i] + pr.bhh[n];
          float hz = ah[1][i] + pr.bhh[HID + n];
          float hn = ah[2][i] + pr.bhh[2*HID + n];
          float rr  = sigm(ir + hr);
          float zz  = sigm(iz + hz);
          float nn  = tanh_f(in + rr*hn);
          hn_buf[s][i] = (1.0f - zz)*nn + zz*hreg[s][i];
        }
      }
      #pragma unroll
      for (int s = 0; s < 2; ++s){
        bool act = (s == 0) || vA1;
        if (act){
          int tt = s ? tA1 : tA0;
          int n = tt*16 + c;
          #pragma unroll
          for (int i = 0; i < 4; ++i){
            int r = g*4 + i;
            if (sm.om[t & 1][r]) hreg[s][i] = hn_buf[s][i];
            exH[(size_t)r*HID + n] = f2bf(hreg[s][i]);
          }
        }
      }
      gsig();
      gwait();
      copyLDS(sm.h_b, LHB, exH, HID);
    }

    // ---- F,G ----
    pm1G();
    pm2R(true);

    // ---- H ----
    if (q == 0){
      #pragma unroll
      for (int q2 = 0; q2 < 2; ++q2){
        int it = tid + q2*NTH;
        int r = it >> 6, d = it & 63;
        float mean = sm.p_f[r*LPF + d];
        float var  = sm.p_f[r*LPF + 64 + d];
        float av   = fabsf(var) + VEPS;
        float inv  = rsqrtf(av);
        float errv = (Xs[q2] - mean)*inv;
        loss += 0.5f*(errv*errv + __logf(av))*Ms[q2];
      }
    }
  }

  __syncthreads();
  #pragma unroll
  for (int s = 0; s < 2; ++s){
    bool act = (s == 0) || vA1;
    if (act){
      int tt = s ? tA1 : tA0;
      int n = tt*16 + c;
      #pragma unroll
      for (int i = 0; i < 4; ++i){
        int r = g*4 + i;
        pr.out_h[(size_t)(row0 + r)*HID + n] = hreg[s][i];
      }
    }
  }
  #pragma unroll
  for (int off = 32; off >= 1; off >>= 1) loss += __shfl_down(loss, off);
  if (lane == 0) sm.red[w] = loss;
  __syncthreads();
  if (tid == 0 && q == 0){
    float ssum = 0.0f;
    for (int i = 0; i < NWAVE; ++i) ssum += sm.red[i];
    pr.partials[G] = ssum;
  }
}

__global__ void k_swz(const float* __restrict__ s, u16* __restrict__ d, int N, int K){
  int i = blockIdx.x*blockDim.x + threadIdx.x;
  if (i >= N*K) return;
  int e    = i & 7;
  int lane = (i >> 3) & 63;
  int rest = i >> 9;
  int ks = K >> 5;
  int k = rest % ks, t = rest / ks;
  int cc = lane & 15, gg = lane >> 4;
  d[i] = f2bf(s[(size_t)(t*16 + cc)*K + (k*32 + gg*8 + e)]);
}

__global__ void k_final(const float* __restrict__ partials, float* __restrict__ out_loss){
  float v = (threadIdx.x < GROUPS) ? partials[threadIdx.x] : 0.0f;
  #pragma unroll
  for (int off = 32; off >= 1; off >>= 1) v += __shfl_down(v, off);
  if (threadIdx.x == 0) out_loss[0] = v;
}

extern "C" void kernel_launch(void* const* d_in, const int* in_sizes, int n_in,
                              void* d_out, int out_size, void* d_ws, size_t ws_size,
                              hipStream_t stream)
{
  const float* X   = (const float*)d_in[0];
  const float* M   = (const float*)d_in[1];
  const int*   obs = (const int*)  d_in[2];
  const float* cov = (const float*)d_in[3];
  const float* Wxz = (const float*)d_in[4];
  const float* bxz = (const float*)d_in[5];
  const float* Wxn = (const float*)d_in[6];
  const float* bxn = (const float*)d_in[7];
  const float* Whz = (const float*)d_in[8];
  const float* Whn = (const float*)d_in[9];
  const float* Wp1 = (const float*)d_in[10];
  const float* bp1 = (const float*)d_in[11];
  const float* Wp2 = (const float*)d_in[12];
  const float* bp2 = (const float*)d_in[13];
  const float* Wc1 = (const float*)d_in[14];
  const float* bc1 = (const float*)d_in[15];
  const float* Wc2 = (const float*)d_in[16];
  const float* bc2 = (const float*)d_in[17];
  const float* Wih = (const float*)d_in[18];
  const float* Whh = (const float*)d_in[19];
  const float* bih = (const float*)d_in[20];
  const float* bhh = (const float*)d_in[21];
  const float* wprep = (const float*)d_in[22];
  const float* bprep = (const float*)d_in[23];

  u16* w = (u16*)d_ws;
  u16* wXZ = w + 0;
  u16* wXN = w + 98304;
  u16* wHZ = w + 196608;
  u16* wHN = w + 786432;
  u16* wP1 = w + 1376256;
  u16* wP2 = w + 1769472;
  u16* wIH = w + 1835008;
  u16* wHH = w + 3309568;
  float*    partials = (float*)((char*)d_ws + 10158080);
  unsigned* cnt      = (unsigned*)((char*)d_ws + 10158336);
  u16*      exch     = (u16*)((char*)d_ws + 10162432);

  struct CV { const float* s; u16* d; int N; int K; } cvs[8] = {
    {Wxz, wXZ, 768, 128}, {Wxn, wXN, 768, 128}, {Whz, wHZ, 768, 768}, {Whn, wHN, 768, 768},
    {Wp1, wP1, 512, 768}, {Wp2, wP2, 128, 512}, {Wih, wIH, 2304, 640}, {Whh, wHH, 2304, 768},
  };
  for (int i = 0; i < 8; ++i){
    int n = cvs[i].N * cvs[i].K;
    k_swz<<<(n + 255)/256, 256, 0, stream>>>(cvs[i].s, cvs[i].d, cvs[i].N, cvs[i].K);
  }
  hipMemsetAsync(cnt, 0, 4096, stream);

  Params pr { X, M, obs, cov, bxz, bxn, bp1, bp2, bc1, bc2, bih, bhh, wprep, bprep,
              Wc1, Wc2, wXZ, wXN, wHZ, wHN, wP1, wP2, wIH, wHH,
              (float*)d_out, partials, exch, cnt };
  nnfo_main<<<NWG, NTH, 0, stream>>>(pr);
  k_final<<<1, 64, 0, stream>>>(partials, (float*)d_out + (size_t)BATCH*HID);
}

// Round 20
// 26334.778 us; speedup vs baseline: 1.0877x; 1.0877x over previous
//
#include <hip/hip_runtime.h>

typedef unsigned short u16;
typedef __attribute__((ext_vector_type(4))) float f32x4;
typedef __attribute__((ext_vector_type(8))) short short8;

#define NUM_T 256
#define BATCH 1024
#define DIM 64
#define HID 768
#define PHID 512
#define PREP 10
#define GIN 640
#define COVSZ 32
#define COVH 128
#define DT_ 0.05f
#define VEPS 1e-6f
#define NTH 512
#define NWAVE 8
#define NWG 256
#define GQ 4
#define GROUPS 64

#define LHB 776
#define LPH 520
#define LPF 132
#define LPB 136
#define LZH 776
#define LGI 648

#define MFMA_ __builtin_amdgcn_mfma_f32_16x16x32_bf16

struct Params {
  const float *X, *M; const int *obs; const float *cov;
  const float *bxz, *bxn, *bp1, *bp2, *bc1, *bc2, *bih, *bhh, *wprep, *bprep;
  const float *Wc1, *Wc2;
  const u16 *Wxz, *Wxn, *Whz, *Whn, *Wp1, *Wp2, *Wih, *Whh;
  float *out_h; float *partials; u16 *exch; unsigned *cnt;
};

__device__ __forceinline__ u16 f2bf(float f){
  unsigned u = __builtin_bit_cast(unsigned, f);
  u = (u + 0x7FFFu + ((u >> 16) & 1u)) >> 16;
  return (u16)u;
}
__device__ __forceinline__ float bf2f(u16 h){
  unsigned u = ((unsigned)h) << 16;
  return __builtin_bit_cast(float, u);
}
__device__ __forceinline__ float sigm(float x){ return 1.0f/(1.0f + __expf(-x)); }
__device__ __forceinline__ float tanh_f(float x){
  float t = __expf(-2.0f*fabsf(x));
  float r = (1.0f - t)/(1.0f + t);
  return x >= 0.0f ? r : -r;
}

struct Smem {
  u16   h_b[16*LHB];
  u16   z_b[16*LHB];
  float p_f[16*LPF];
  u16   p_b[16*LPB];
  union {
    u16 zh[16*LZH];
    u16 gi[16*LGI];
    u16 ph1[16*LPH];
  } u;
  int om[2][16];
  float red[NWAVE];
};

// Depth-2 NT-slot paced GEMM; r20: ONE s_barrier per even/odd chunk pair
// (was per chunk). Values and per-accumulator k-order unchanged -> same bits.
template<int NKC, int NT>
__device__ __forceinline__ void dotP(const u16* __restrict__ A, int lda,
    const u16* __restrict__ W2, int tile0, f32x4* acc,
    int c, int g, int lane, int w)
{
  static_assert((NKC & 1) == 0, "NKC must be even");
  const u16* a = A + c*lda + g*8;
  const short8* base[NT];
  #pragma unroll
  for (int j = 0; j < NT; ++j)
    base[j] = (const short8*)(W2 + ((size_t)(tile0 + w + 8*j)*NKC)*512) + lane;
  short8 ldA[NT], ldB[NT];
  #pragma unroll
  for (int j = 0; j < NT; ++j) ldA[j] = base[j][0];
  #pragma unroll
  for (int j = 0; j < NT; ++j) ldB[j] = base[j][64];
  __builtin_amdgcn_s_barrier();
  #pragma unroll 1
  for (int kp = 0; kp < NKC/2 - 1; ++kp){
    int kk = 2*kp;
    {
      short8 av = *(const short8*)(a + 32*kk);
      #pragma unroll
      for (int j = 0; j < NT; ++j) acc[j] = MFMA_(av, ldA[j], acc[j], 0, 0, 0);
      #pragma unroll
      for (int j = 0; j < NT; ++j) ldA[j] = base[j][64*(kk + 2)];
    }
    {
      short8 av = *(const short8*)(a + 32*(kk + 1));
      #pragma unroll
      for (int j = 0; j < NT; ++j) acc[j] = MFMA_(av, ldB[j], acc[j], 0, 0, 0);
      #pragma unroll
      for (int j = 0; j < NT; ++j) ldB[j] = base[j][64*(kk + 3)];
    }
    __builtin_amdgcn_s_barrier();
  }
  {
    short8 av = *(const short8*)(a + 32*(NKC - 2));
    #pragma unroll
    for (int j = 0; j < NT; ++j) acc[j] = MFMA_(av, ldA[j], acc[j], 0, 0, 0);
    av = *(const short8*)(a + 32*(NKC - 1));
    #pragma unroll
    for (int j = 0; j < NT; ++j) acc[j] = MFMA_(av, ldB[j], acc[j], 0, 0, 0);
    __builtin_amdgcn_s_barrier();
  }
}

// Depth-2 guarded 2-slot GEMM; one barrier per pair (r20).
template<int NKC>
__device__ __forceinline__ void dotPG(const u16* __restrict__ A, int lda,
    const u16* __restrict__ W2, int t0, int t1, bool v1, f32x4* acc,
    int c, int g, int lane)
{
  static_assert((NKC & 1) == 0, "NKC must be even");
  const u16* a = A + c*lda + g*8;
  const short8* b0 = (const short8*)(W2 + ((size_t)t0*NKC)*512) + lane;
  const short8* b1 = (const short8*)(W2 + ((size_t)t1*NKC)*512) + lane;
  short8 A0, B0, A1v, B1v;
  A0 = b0[0]; B0 = b0[64];
  if (v1){ A1v = b1[0]; B1v = b1[64]; }
  __builtin_amdgcn_s_barrier();
  #pragma unroll 1
  for (int kp = 0; kp < NKC/2 - 1; ++kp){
    int kk = 2*kp;
    {
      short8 av = *(const short8*)(a + 32*kk);
      acc[0] = MFMA_(av, A0, acc[0], 0, 0, 0);
      if (v1) acc[1] = MFMA_(av, A1v, acc[1], 0, 0, 0);
      A0 = b0[64*(kk + 2)];
      if (v1) A1v = b1[64*(kk + 2)];
    }
    {
      short8 av = *(const short8*)(a + 32*(kk + 1));
      acc[0] = MFMA_(av, B0, acc[0], 0, 0, 0);
      if (v1) acc[1] = MFMA_(av, B1v, acc[1], 0, 0, 0);
      B0 = b0[64*(kk + 3)];
      if (v1) B1v = b1[64*(kk + 3)];
    }
    __builtin_amdgcn_s_barrier();
  }
  {
    short8 av = *(const short8*)(a + 32*(NKC - 2));
    acc[0] = MFMA_(av, A0, acc[0], 0, 0, 0);
    if (v1) acc[1] = MFMA_(av, A1v, acc[1], 0, 0, 0);
    av = *(const short8*)(a + 32*(NKC - 1));
    acc[0] = MFMA_(av, B0, acc[0], 0, 0, 0);
    if (v1) acc[1] = MFMA_(av, B1v, acc[1], 0, 0, 0);
    __builtin_amdgcn_s_barrier();
  }
}

// Depth-2 guarded 3-gate streamer; one barrier per pair (r20), unconditional.
template<int NKC>
__device__ __forceinline__ void dot3PG(const u16* __restrict__ A, int lda,
    const u16* __restrict__ W2, int t0, bool act, f32x4* acc, int c, int g, int lane)
{
  static_assert((NKC & 1) == 0, "NKC must be even");
  const u16* a = A + c*lda + g*8;
  const short8* base[3];
  #pragma unroll
  for (int j = 0; j < 3; ++j)
    base[j] = (const short8*)(W2 + ((size_t)(t0 + 48*j)*NKC)*512) + lane;
  short8 ldA[3], ldB[3];
  if (act){
    #pragma unroll
    for (int j = 0; j < 3; ++j) ldA[j] = base[j][0];
    #pragma unroll
    for (int j = 0; j < 3; ++j) ldB[j] = base[j][64];
  }
  __builtin_amdgcn_s_barrier();
  #pragma unroll 1
  for (int kp = 0; kp < NKC/2 - 1; ++kp){
    int kk = 2*kp;
    if (act){
      short8 av = *(const short8*)(a + 32*kk);
      #pragma unroll
      for (int j = 0; j < 3; ++j) acc[j] = MFMA_(av, ldA[j], acc[j], 0, 0, 0);
      #pragma unroll
      for (int j = 0; j < 3; ++j) ldA[j] = base[j][64*(kk + 2)];
      av = *(const short8*)(a + 32*(kk + 1));
      #pragma unroll
      for (int j = 0; j < 3; ++j) acc[j] = MFMA_(av, ldB[j], acc[j], 0, 0, 0);
      #pragma unroll
      for (int j = 0; j < 3; ++j) ldB[j] = base[j][64*(kk + 3)];
    }
    __builtin_amdgcn_s_barrier();
  }
  if (act){
    short8 av = *(const short8*)(a + 32*(NKC - 2));
    #pragma unroll
    for (int j = 0; j < 3; ++j) acc[j] = MFMA_(av, ldA[j], acc[j], 0, 0, 0);
    av = *(const short8*)(a + 32*(NKC - 1));
    #pragma unroll
    for (int j = 0; j < 3; ++j) acc[j] = MFMA_(av, ldB[j], acc[j], 0, 0, 0);
  }
  __builtin_amdgcn_s_barrier();
}

// Replicated pm2 (8 tiles, wave w owns tile w), NKC=16 (r12-verified).
__device__ __forceinline__ void dotPB16(const u16* __restrict__ A, int lda,
    const u16* __restrict__ W2, f32x4* acc, int c, int g, int lane, int w)
{
  const u16* a = A + c*lda + g*8;
  const short8* base = (const short8*)(W2 + ((size_t)w*16)*512) + lane;
  short8 ldA[4], ldB[4];
  #pragma unroll
  for (int m = 0; m < 4; ++m) ldA[m] = base[64*m];
  #pragma unroll
  for (int m = 0; m < 4; ++m) ldB[m] = base[64*(4 + m)];
  __builtin_amdgcn_s_barrier();
  #pragma unroll
  for (int m = 0; m < 4; ++m){
    short8 av = *(const short8*)(a + 32*m);
    acc[0] = MFMA_(av, ldA[m], acc[0], 0, 0, 0);
  }
  #pragma unroll
  for (int m = 0; m < 4; ++m) ldA[m] = base[64*(8 + m)];
  __builtin_amdgcn_s_barrier();
  #pragma unroll
  for (int m = 0; m < 4; ++m){
    short8 av = *(const short8*)(a + 32*(4 + m));
    acc[0] = MFMA_(av, ldB[m], acc[0], 0, 0, 0);
  }
  #pragma unroll
  for (int m = 0; m < 4; ++m) ldB[m] = base[64*(12 + m)];
  __builtin_amdgcn_s_barrier();
  #pragma unroll
  for (int m = 0; m < 4; ++m){
    short8 av = *(const short8*)(a + 32*(8 + m));
    acc[0] = MFMA_(av, ldA[m], acc[0], 0, 0, 0);
  }
  __builtin_amdgcn_s_barrier();
  #pragma unroll
  for (int m = 0; m < 4; ++m){
    short8 av = *(const short8*)(a + 32*(12 + m));
    acc[0] = MFMA_(av, ldB[m], acc[0], 0, 0, 0);
  }
  __builtin_amdgcn_s_barrier();
}

__global__ __launch_bounds__(NTH)
void nnfo_main(Params pr)
{
  __shared__ Smem sm;
  const int tid  = threadIdx.x;
  const int lane = tid & 63;
  const int w    = tid >> 6;
  const int c = lane & 15;
  const int g = lane >> 4;
  const int b = blockIdx.x;
  const int q    = (b >> 3) & 3;
  const int G    = (b & 7)*8 + (b >> 5);    // group's 4 WGs share an XCD
  const int row0 = G * 16;

  u16* exZH = pr.exch + (size_t)G*32768;
  u16* exH  = exZH + 16*HID;
  u16* exP1 = exH  + 16*HID;
  unsigned* cnt = pr.cnt + G*16;

  unsigned gen = 0;
  auto gsync = [&](){
    __syncthreads();
    if (tid == 0)
      __hip_atomic_fetch_add(cnt, 1u, __ATOMIC_RELEASE, __HIP_MEMORY_SCOPE_AGENT);
    gen += GQ;
    if (tid == 0){
      int spins = 0;
      while (__hip_atomic_load(cnt, __ATOMIC_ACQUIRE, __HIP_MEMORY_SCOPE_AGENT) < gen){
        __builtin_amdgcn_s_sleep(1);
        if (++spins > 8000000) break;
      }
    }
    __syncthreads();
  };
  auto copyLDS = [&](u16* dst, int ldst, const u16* src, int wcols){
    int nb = 16*(wcols >> 3);
    for (int idx = tid; idx < nb; idx += NTH){
      int r = idx/(wcols >> 3), cb = idx - r*(wcols >> 3);
      *(short8*)(dst + r*ldst + cb*8) = *(const short8*)(src + (size_t)r*wcols + cb*8);
    }
    __syncthreads();
  };

  const int  tA0 = q*12 + w;
  const int  tA1 = (w < 4) ? (q*12 + w + 8) : (q*12 + w);
  const bool vA1 = (w < 4);
  const int  tP  = q*8 + w;

  float loss = 0.0f;
  float hreg[2][4];

  // ---- prologue ----
  for (int it = tid; it < 16*COVH; it += NTH){
    int r = it >> 7, j = it & 127;
    float acc = pr.bc1[j];
    const float* cv = pr.cov + (size_t)(row0 + r)*COVSZ;
    const float* wv = pr.Wc1 + (size_t)j*COVSZ;
    for (int k = 0; k < COVSZ; ++k) acc += cv[k]*wv[k];
    sm.p_f[r*LPF + j] = fmaxf(acc, 0.0f);
  }
  __syncthreads();
  for (int it = tid; it < 16*HID; it += NTH){
    int r = it / HID, j = it - r*HID;
    float acc = pr.bc2[j];
    const float* wv = pr.Wc2 + (size_t)j*COVH;
    for (int k = 0; k < COVH; ++k) acc += sm.p_f[r*LPF + k]*wv[k];
    sm.h_b[r*LHB + j] = f2bf(tanh_f(acc));
  }
  #pragma unroll
  for (int s = 0; s < 2; ++s){
    bool act = (s == 0) || vA1;
    int tt = s ? tA1 : tA0;
    int n = tt*16 + c;
    const float* wv = pr.Wc2 + (size_t)n*COVH;
    #pragma unroll
    for (int i = 0; i < 4; ++i){
      int r = g*4 + i;
      float acc = pr.bc2[n];
      for (int k = 0; k < COVH; ++k) acc += sm.p_f[r*LPF + k]*wv[k];
      hreg[s][i] = act ? tanh_f(acc) : 0.0f;
    }
  }
  __syncthreads();

  auto pm1G = [&](){
    f32x4 acc[1] = {};
    dotP<24, 1>(sm.h_b, LHB, pr.Wp1, q*8, acc, c, g, lane, w);
    int n = tP*16 + c;
    float bb = pr.bp1[n];
    #pragma unroll
    for (int i = 0; i < 4; ++i)
      exP1[(size_t)(g*4 + i)*PHID + n] = f2bf(fmaxf(acc[0][i] + bb, 0.0f));
    gsync();
    copyLDS(sm.u.ph1, LPH, exP1, PHID);
  };
  auto pm2R = [&](bool write_pb){
    f32x4 acc[1] = {};
    dotPB16(sm.u.ph1, LPH, pr.Wp2, acc, c, g, lane, w);
    int n = w*16 + c;
    float bb = pr.bp2[n];
    #pragma unroll
    for (int i = 0; i < 4; ++i){
      float v = acc[0][i] + bb;
      sm.p_f[(g*4 + i)*LPF + n] = v;
      if (write_pb) sm.p_b[(g*4 + i)*LPB + n] = f2bf(v);
    }
    __syncthreads();
  };

  pm1G();
  pm2R(true);

  float Xs[2], Ms[2];

  #pragma unroll 1
  for (int t = 0; t < NUM_T; ++t){
    if (tid < 16) sm.om[t & 1][tid] = pr.obs[(size_t)t*BATCH + row0 + tid];
    float Xpre[2];
    #pragma unroll
    for (int q2 = 0; q2 < 2; ++q2){
      int it = tid + q2*NTH;
      int r = it >> 6, d = it & 63;
      Xpre[q2] = pr.X[((size_t)t*BATCH + row0 + r)*DIM + d];
    }

    // ---- A1: z at owned cols; publish zh slice ----
    {
      f32x4 accz[2] = {};
      dotPG<4>(sm.p_b, LPB, pr.Wxz, tA0, tA1, vA1, accz, c, g, lane);
      dotPG<24>(sm.h_b, LHB, pr.Whz, tA0, tA1, vA1, accz, c, g, lane);
      #pragma unroll
      for (int s = 0; s < 2; ++s){
        bool act = (s == 0) || vA1;
        if (act){
          int tt = s ? tA1 : tA0;
          int n = tt*16 + c;
          float bb = pr.bxz[n];
          #pragma unroll
          for (int i = 0; i < 4; ++i){
            int r = g*4 + i;
            float z = sigm(accz[s][i] + bb);
            sm.z_b[r*LHB + n] = f2bf(z);
            exZH[(size_t)r*HID + n] = f2bf(z*hreg[s][i]);
          }
        }
      }
      gsync();
      copyLDS(sm.u.zh, LZH, exZH, HID);
    }
    // ---- A2: h ODE update at owned cols; publish h slice ----
    {
      f32x4 accn[2] = {};
      dotPG<4>(sm.p_b, LPB, pr.Wxn, tA0, tA1, vA1, accn, c, g, lane);
      dotPG<24>(sm.u.zh, LZH, pr.Whn, tA0, tA1, vA1, accn, c, g, lane);
      #pragma unroll
      for (int s = 0; s < 2; ++s){
        bool act = (s == 0) || vA1;
        if (act){
          int tt = s ? tA1 : tA0;
          int n = tt*16 + c;
          float bb = pr.bxn[n];
          #pragma unroll
          for (int i = 0; i < 4; ++i){
            int r = g*4 + i;
            float nv = tanh_f(accn[s][i] + bb);
            float z  = bf2f(sm.z_b[r*LHB + n]);
            float h  = hreg[s][i];
            h = h + DT_*(1.0f - z)*(nv - h);
            hreg[s][i] = h;
            exH[(size_t)r*HID + n] = f2bf(h);
          }
        }
      }
      gsync();
      copyLDS(sm.h_b, LHB, exH, HID);
    }

    // ---- B,C ----
    pm1G();
    pm2R(false);

    // ---- D ----
    #pragma unroll
    for (int q2 = 0; q2 < 2; ++q2){
      int it = tid + q2*NTH;
      int r = it >> 6, d = it & 63;
      size_t xoff = ((size_t)t*BATCH + row0 + r)*DIM + d;
      float Xv = Xpre[q2];
      float om = sm.om[t & 1][r] ? 1.0f : 0.0f;
      float Mv = pr.M[xoff] * om;
      Xs[q2] = Xv; Ms[q2] = Mv;
      float mean = sm.p_f[r*LPF + d];
      float var  = sm.p_f[r*LPF + 64 + d];
      float av   = fabsf(var) + VEPS;
      float inv  = rsqrtf(av);
      float errv = (Xv - mean)*inv;
      if (q == 0) loss += 0.5f*(errv*errv + __logf(av))*Mv;
      #pragma unroll
      for (int p = 0; p < PREP; ++p){
        float s = pr.bprep[d*PREP + p]
                + Xv  * pr.wprep[(d*4 + 0)*PREP + p]
                + mean* pr.wprep[(d*4 + 1)*PREP + p]
                + av  * pr.wprep[(d*4 + 2)*PREP + p]
                + errv* pr.wprep[(d*4 + 3)*PREP + p];
        sm.u.gi[r*LGI + d*PREP + p] = f2bf(fmaxf(s, 0.0f)*Mv);
      }
    }
    __syncthreads();

    // ---- E: GRUCell jump at owned cols; publish h slice ----
    {
      float hn_buf[2][4];
      #pragma unroll 1
      for (int s = 0; s < 2; ++s){
        bool act = (s == 0) || vA1;
        int ht = s ? tA1 : tA0;
        int n = ht*16 + c;
        f32x4 ai[3] = {};
        dot3PG<20>(sm.u.gi, LGI, pr.Wih, ht, act, ai, c, g, lane);
        f32x4 ah[3] = {};
        dot3PG<24>(sm.h_b, LHB, pr.Whh, ht, act, ah, c, g, lane);
        #pragma unroll
        for (int i = 0; i < 4; ++i){
          float ir = ai[0][i] + pr.bih[n];
          float iz = ai[1][i] + pr.bih[HID + n];
          float in = ai[2][i] + pr.bih[2*HID + n];
          float hr = ah[0][i] + pr.bhh[n];
          float hz = ah[1][i] + pr.bhh[HID + n];
          float hn = ah[2][i] + pr.bhh[2*HID + n];
          float rr  = sigm(ir + hr);
          float zz  = sigm(iz + hz);
          float nn  = tanh_f(in + rr*hn);
          hn_buf[s][i] = (1.0f - zz)*nn + zz*hreg[s][i];
        }
      }
      #pragma unroll
      for (int s = 0; s < 2; ++s){
        bool act = (s == 0) || vA1;
        if (act){
          int tt = s ? tA1 : tA0;
          int n = tt*16 + c;
          #pragma unroll
          for (int i = 0; i < 4; ++i){
            int r = g*4 + i;
            if (sm.om[t & 1][r]) hreg[s][i] = hn_buf[s][i];
            exH[(size_t)r*HID + n] = f2bf(hreg[s][i]);
          }
        }
      }
      gsync();
      copyLDS(sm.h_b, LHB, exH, HID);
    }

    // ---- F,G ----
    pm1G();
    pm2R(true);

    // ---- H ----
    if (q == 0){
      #pragma unroll
      for (int q2 = 0; q2 < 2; ++q2){
        int it = tid + q2*NTH;
        int r = it >> 6, d = it & 63;
        float mean = sm.p_f[r*LPF + d];
        float var  = sm.p_f[r*LPF + 64 + d];
        float av   = fabsf(var) + VEPS;
        float inv  = rsqrtf(av);
        float errv = (Xs[q2] - mean)*inv;
        loss += 0.5f*(errv*errv + __logf(av))*Ms[q2];
      }
    }
  }

  __syncthreads();
  #pragma unroll
  for (int s = 0; s < 2; ++s){
    bool act = (s == 0) || vA1;
    if (act){
      int tt = s ? tA1 : tA0;
      int n = tt*16 + c;
      #pragma unroll
      for (int i = 0; i < 4; ++i){
        int r = g*4 + i;
        pr.out_h[(size_t)(row0 + r)*HID + n] = hreg[s][i];
      }
    }
  }
  #pragma unroll
  for (int off = 32; off >= 1; off >>= 1) loss += __shfl_down(loss, off);
  if (lane == 0) sm.red[w] = loss;
  __syncthreads();
  if (tid == 0 && q == 0){
    float ssum = 0.0f;
    for (int i = 0; i < NWAVE; ++i) ssum += sm.red[i];
    pr.partials[G] = ssum;
  }
}

__global__ void k_swz(const float* __restrict__ s, u16* __restrict__ d, int N, int K){
  int i = blockIdx.x*blockDim.x + threadIdx.x;
  if (i >= N*K) return;
  int e    = i & 7;
  int lane = (i >> 3) & 63;
  int rest = i >> 9;
  int ks = K >> 5;
  int k = rest % ks, t = rest / ks;
  int cc = lane & 15, gg = lane >> 4;
  d[i] = f2bf(s[(size_t)(t*16 + cc)*K + (k*32 + gg*8 + e)]);
}

__global__ void k_final(const float* __restrict__ partials, float* __restrict__ out_loss){
  float v = (threadIdx.x < GROUPS) ? partials[threadIdx.x] : 0.0f;
  #pragma unroll
  for (int off = 32; off >= 1; off >>= 1) v += __shfl_down(v, off);
  if (threadIdx.x == 0) out_loss[0] = v;
}

extern "C" void kernel_launch(void* const* d_in, const int* in_sizes, int n_in,
                              void* d_out, int out_size, void* d_ws, size_t ws_size,
                              hipStream_t stream)
{
  const float* X   = (const float*)d_in[0];
  const float* M   = (const float*)d_in[1];
  const int*   obs = (const int*)  d_in[2];
  const float* cov = (const float*)d_in[3];
  const float* Wxz = (const float*)d_in[4];
  const float* bxz = (const float*)d_in[5];
  const float* Wxn = (const float*)d_in[6];
  const float* bxn = (const float*)d_in[7];
  const float* Whz = (const float*)d_in[8];
  const float* Whn = (const float*)d_in[9];
  const float* Wp1 = (const float*)d_in[10];
  const float* bp1 = (const float*)d_in[11];
  const float* Wp2 = (const float*)d_in[12];
  const float* bp2 = (const float*)d_in[13];
  const float* Wc1 = (const float*)d_in[14];
  const float* bc1 = (const float*)d_in[15];
  const float* Wc2 = (const float*)d_in[16];
  const float* bc2 = (const float*)d_in[17];
  const float* Wih = (const float*)d_in[18];
  const float* Whh = (const float*)d_in[19];
  const float* bih = (const float*)d_in[20];
  const float* bhh = (const float*)d_in[21];
  const float* wprep = (const float*)d_in[22];
  const float* bprep = (const float*)d_in[23];

  u16* w = (u16*)d_ws;
  u16* wXZ = w + 0;
  u16* wXN = w + 98304;
  u16* wHZ = w + 196608;
  u16* wHN = w + 786432;
  u16* wP1 = w + 1376256;
  u16* wP2 = w + 1769472;
  u16* wIH = w + 1835008;
  u16* wHH = w + 3309568;
  float*    partials = (float*)((char*)d_ws + 10158080);
  unsigned* cnt      = (unsigned*)((char*)d_ws + 10158336);
  u16*      exch     = (u16*)((char*)d_ws + 10162432);

  struct CV { const float* s; u16* d; int N; int K; } cvs[8] = {
    {Wxz, wXZ, 768, 128}, {Wxn, wXN, 768, 128}, {Whz, wHZ, 768, 768}, {Whn, wHN, 768, 768},
    {Wp1, wP1, 512, 768}, {Wp2, wP2, 128, 512}, {Wih, wIH, 2304, 640}, {Whh, wHH, 2304, 768},
  };
  for (int i = 0; i < 8; ++i){
    int n = cvs[i].N * cvs[i].K;
    k_swz<<<(n + 255)/256, 256, 0, stream>>>(cvs[i].s, cvs[i].d, cvs[i].N, cvs[i].K);
  }
  hipMemsetAsync(cnt, 0, 4096, stream);

  Params pr { X, M, obs, cov, bxz, bxn, bp1, bp2, bc1, bc2, bih, bhh, wprep, bprep,
              Wc1, Wc2, wXZ, wXN, wHZ, wHN, wP1, wP2, wIH, wHH,
              (float*)d_out, partials, exch, cnt };
  nnfo_main<<<NWG, NTH, 0, stream>>>(pr);
  k_final<<<1, 64, 0, stream>>>(partials, (float*)d_out + (size_t)BATCH*HID);
}

// Round 21
// 23936.139 us; speedup vs baseline: 1.1967x; 1.1002x over previous
//
#include <hip/hip_runtime.h>

typedef unsigned short u16;
typedef __attribute__((ext_vector_type(4))) float f32x4;
typedef __attribute__((ext_vector_type(8))) short short8;

#define NUM_T 256
#define BATCH 1024
#define DIM 64
#define HID 768
#define PHID 512
#define PREP 10
#define GIN 640
#define COVSZ 32
#define COVH 128
#define DT_ 0.05f
#define VEPS 1e-6f
#define NTH 512
#define NWAVE 8
#define NWG 256
#define GQ 4
#define GROUPS 64

#define LHB 776
#define LPH 520
#define LPF 132
#define LPB 136
#define LZH 776
#define LGI 648

#define MFMA_ __builtin_amdgcn_mfma_f32_16x16x32_bf16

struct Params {
  const float *X, *M; const int *obs; const float *cov;
  const float *bxz, *bxn, *bp1, *bp2, *bc1, *bc2, *bih, *bhh, *wprep, *bprep;
  const float *Wc1, *Wc2;
  const u16 *Wxz, *Wxn, *Whz, *Whn, *Wp1, *Wp2, *Wih, *Whh;
  float *out_h; float *partials; u16 *exch; unsigned *cnt;
};

__device__ __forceinline__ u16 f2bf(float f){
  unsigned u = __builtin_bit_cast(unsigned, f);
  u = (u + 0x7FFFu + ((u >> 16) & 1u)) >> 16;
  return (u16)u;
}
__device__ __forceinline__ float bf2f(u16 h){
  unsigned u = ((unsigned)h) << 16;
  return __builtin_bit_cast(float, u);
}
__device__ __forceinline__ float sigm(float x){ return 1.0f/(1.0f + __expf(-x)); }
__device__ __forceinline__ float tanh_f(float x){
  float t = __expf(-2.0f*fabsf(x));
  float r = (1.0f - t)/(1.0f + t);
  return x >= 0.0f ? r : -r;
}

struct Smem {
  u16   h_b[16*LHB];
  u16   z_b[16*LHB];
  float p_f[16*LPF];
  u16   p_b[16*LPB];
  union {
    u16 zh[16*LZH];
    u16 gi[16*LGI];
    u16 ph1[16*LPH];
  } u;
  int om[2][16];
  float red[NWAVE];
};

// Depth-2 NT-slot paced GEMM; one s_barrier per even/odd chunk pair (r20).
// Values and per-accumulator k-order = r12/r17/r18 -> bit-identical.
template<int NKC, int NT>
__device__ __forceinline__ void dotP(const u16* __restrict__ A, int lda,
    const u16* __restrict__ W2, int tile0, f32x4* acc,
    int c, int g, int lane, int w)
{
  static_assert((NKC & 1) == 0, "NKC must be even");
  const u16* a = A + c*lda + g*8;
  const short8* base[NT];
  #pragma unroll
  for (int j = 0; j < NT; ++j)
    base[j] = (const short8*)(W2 + ((size_t)(tile0 + w + 8*j)*NKC)*512) + lane;
  short8 ldA[NT], ldB[NT];
  #pragma unroll
  for (int j = 0; j < NT; ++j) ldA[j] = base[j][0];
  #pragma unroll
  for (int j = 0; j < NT; ++j) ldB[j] = base[j][64];
  __builtin_amdgcn_s_barrier();
  #pragma unroll 1
  for (int kp = 0; kp < NKC/2 - 1; ++kp){
    int kk = 2*kp;
    {
      short8 av = *(const short8*)(a + 32*kk);
      #pragma unroll
      for (int j = 0; j < NT; ++j) acc[j] = MFMA_(av, ldA[j], acc[j], 0, 0, 0);
      #pragma unroll
      for (int j = 0; j < NT; ++j) ldA[j] = base[j][64*(kk + 2)];
    }
    {
      short8 av = *(const short8*)(a + 32*(kk + 1));
      #pragma unroll
      for (int j = 0; j < NT; ++j) acc[j] = MFMA_(av, ldB[j], acc[j], 0, 0, 0);
      #pragma unroll
      for (int j = 0; j < NT; ++j) ldB[j] = base[j][64*(kk + 3)];
    }
    __builtin_amdgcn_s_barrier();
  }
  {
    short8 av = *(const short8*)(a + 32*(NKC - 2));
    #pragma unroll
    for (int j = 0; j < NT; ++j) acc[j] = MFMA_(av, ldA[j], acc[j], 0, 0, 0);
    av = *(const short8*)(a + 32*(NKC - 1));
    #pragma unroll
    for (int j = 0; j < NT; ++j) acc[j] = MFMA_(av, ldB[j], acc[j], 0, 0, 0);
    __builtin_amdgcn_s_barrier();
  }
}

// Depth-2 guarded 2-slot GEMM; one barrier per pair.
template<int NKC>
__device__ __forceinline__ void dotPG(const u16* __restrict__ A, int lda,
    const u16* __restrict__ W2, int t0, int t1, bool v1, f32x4* acc,
    int c, int g, int lane)
{
  static_assert((NKC & 1) == 0, "NKC must be even");
  const u16* a = A + c*lda + g*8;
  const short8* b0 = (const short8*)(W2 + ((size_t)t0*NKC)*512) + lane;
  const short8* b1 = (const short8*)(W2 + ((size_t)t1*NKC)*512) + lane;
  short8 A0, B0, A1v, B1v;
  A0 = b0[0]; B0 = b0[64];
  if (v1){ A1v = b1[0]; B1v = b1[64]; }
  __builtin_amdgcn_s_barrier();
  #pragma unroll 1
  for (int kp = 0; kp < NKC/2 - 1; ++kp){
    int kk = 2*kp;
    {
      short8 av = *(const short8*)(a + 32*kk);
      acc[0] = MFMA_(av, A0, acc[0], 0, 0, 0);
      if (v1) acc[1] = MFMA_(av, A1v, acc[1], 0, 0, 0);
      A0 = b0[64*(kk + 2)];
      if (v1) A1v = b1[64*(kk + 2)];
    }
    {
      short8 av = *(const short8*)(a + 32*(kk + 1));
      acc[0] = MFMA_(av, B0, acc[0], 0, 0, 0);
      if (v1) acc[1] = MFMA_(av, B1v, acc[1], 0, 0, 0);
      B0 = b0[64*(kk + 3)];
      if (v1) B1v = b1[64*(kk + 3)];
    }
    __builtin_amdgcn_s_barrier();
  }
  {
    short8 av = *(const short8*)(a + 32*(NKC - 2));
    acc[0] = MFMA_(av, A0, acc[0], 0, 0, 0);
    if (v1) acc[1] = MFMA_(av, A1v, acc[1], 0, 0, 0);
    av = *(const short8*)(a + 32*(NKC - 1));
    acc[0] = MFMA_(av, B0, acc[0], 0, 0, 0);
    if (v1) acc[1] = MFMA_(av, B1v, acc[1], 0, 0, 0);
    __builtin_amdgcn_s_barrier();
  }
}

// Depth-2 guarded 3-gate streamer; one barrier per pair, unconditional.
template<int NKC>
__device__ __forceinline__ void dot3PG(const u16* __restrict__ A, int lda,
    const u16* __restrict__ W2, int t0, bool act, f32x4* acc, int c, int g, int lane)
{
  static_assert((NKC & 1) == 0, "NKC must be even");
  const u16* a = A + c*lda + g*8;
  const short8* base[3];
  #pragma unroll
  for (int j = 0; j < 3; ++j)
    base[j] = (const short8*)(W2 + ((size_t)(t0 + 48*j)*NKC)*512) + lane;
  short8 ldA[3], ldB[3];
  if (act){
    #pragma unroll
    for (int j = 0; j < 3; ++j) ldA[j] = base[j][0];
    #pragma unroll
    for (int j = 0; j < 3; ++j) ldB[j] = base[j][64];
  }
  __builtin_amdgcn_s_barrier();
  #pragma unroll 1
  for (int kp = 0; kp < NKC/2 - 1; ++kp){
    int kk = 2*kp;
    if (act){
      short8 av = *(const short8*)(a + 32*kk);
      #pragma unroll
      for (int j = 0; j < 3; ++j) acc[j] = MFMA_(av, ldA[j], acc[j], 0, 0, 0);
      #pragma unroll
      for (int j = 0; j < 3; ++j) ldA[j] = base[j][64*(kk + 2)];
      av = *(const short8*)(a + 32*(kk + 1));
      #pragma unroll
      for (int j = 0; j < 3; ++j) acc[j] = MFMA_(av, ldB[j], acc[j], 0, 0, 0);
      #pragma unroll
      for (int j = 0; j < 3; ++j) ldB[j] = base[j][64*(kk + 3)];
    }
    __builtin_amdgcn_s_barrier();
  }
  if (act){
    short8 av = *(const short8*)(a + 32*(NKC - 2));
    #pragma unroll
    for (int j = 0; j < 3; ++j) acc[j] = MFMA_(av, ldA[j], acc[j], 0, 0, 0);
    av = *(const short8*)(a + 32*(NKC - 1));
    #pragma unroll
    for (int j = 0; j < 3; ++j) acc[j] = MFMA_(av, ldB[j], acc[j], 0, 0, 0);
  }
  __builtin_amdgcn_s_barrier();
}

// Replicated pm2 (8 tiles, wave w owns tile w), NKC=16 (r12-verified).
__device__ __forceinline__ void dotPB16(const u16* __restrict__ A, int lda,
    const u16* __restrict__ W2, f32x4* acc, int c, int g, int lane, int w)
{
  const u16* a = A + c*lda + g*8;
  const short8* base = (const short8*)(W2 + ((size_t)w*16)*512) + lane;
  short8 ldA[4], ldB[4];
  #pragma unroll
  for (int m = 0; m < 4; ++m) ldA[m] = base[64*m];
  #pragma unroll
  for (int m = 0; m < 4; ++m) ldB[m] = base[64*(4 + m)];
  __builtin_amdgcn_s_barrier();
  #pragma unroll
  for (int m = 0; m < 4; ++m){
    short8 av = *(const short8*)(a + 32*m);
    acc[0] = MFMA_(av, ldA[m], acc[0], 0, 0, 0);
  }
  #pragma unroll
  for (int m = 0; m < 4; ++m) ldA[m] = base[64*(8 + m)];
  __builtin_amdgcn_s_barrier();
  #pragma unroll
  for (int m = 0; m < 4; ++m){
    short8 av = *(const short8*)(a + 32*(4 + m));
    acc[0] = MFMA_(av, ldB[m], acc[0], 0, 0, 0);
  }
  #pragma unroll
  for (int m = 0; m < 4; ++m) ldB[m] = base[64*(12 + m)];
  __builtin_amdgcn_s_barrier();
  #pragma unroll
  for (int m = 0; m < 4; ++m){
    short8 av = *(const short8*)(a + 32*(8 + m));
    acc[0] = MFMA_(av, ldA[m], acc[0], 0, 0, 0);
  }
  __builtin_amdgcn_s_barrier();
  #pragma unroll
  for (int m = 0; m < 4; ++m){
    short8 av = *(const short8*)(a + 32*(12 + m));
    acc[0] = MFMA_(av, ldB[m], acc[0], 0, 0, 0);
  }
  __builtin_amdgcn_s_barrier();
}

__global__ __launch_bounds__(NTH)
void nnfo_main(Params pr)
{
  __shared__ Smem sm;
  const int tid  = threadIdx.x;
  const int lane = tid & 63;
  const int w    = tid >> 6;
  const int c = lane & 15;
  const int g = lane >> 4;
  const int b = blockIdx.x;
  const int q    = (b >> 3) & 3;
  const int G    = (b & 7)*8 + (b >> 5);    // group's 4 WGs share an XCD
  const int row0 = G * 16;

  u16* exZH = pr.exch + (size_t)G*32768;
  u16* exH  = exZH + 16*HID;
  unsigned* cnt = pr.cnt + G*16;

  unsigned gen = 0;
  auto gsync = [&](){
    __syncthreads();
    if (tid == 0)
      __hip_atomic_fetch_add(cnt, 1u, __ATOMIC_RELEASE, __HIP_MEMORY_SCOPE_AGENT);
    gen += GQ;
    if (tid == 0){
      int spins = 0;
      while (__hip_atomic_load(cnt, __ATOMIC_ACQUIRE, __HIP_MEMORY_SCOPE_AGENT) < gen){
        __builtin_amdgcn_s_sleep(1);
        if (++spins > 8000000) break;
      }
    }
    __syncthreads();
  };
  auto copyLDS = [&](u16* dst, int ldst, const u16* src, int wcols){
    int nb = 16*(wcols >> 3);
    for (int idx = tid; idx < nb; idx += NTH){
      int r = idx/(wcols >> 3), cb = idx - r*(wcols >> 3);
      *(short8*)(dst + r*ldst + cb*8) = *(const short8*)(src + (size_t)r*wcols + cb*8);
    }
    __syncthreads();
  };

  const int  tA0 = q*12 + w;
  const int  tA1 = (w < 4) ? (q*12 + w + 8) : (q*12 + w);
  const bool vA1 = (w < 4);

  float loss = 0.0f;
  float hreg[2][4];

  // ---- prologue ----
  for (int it = tid; it < 16*COVH; it += NTH){
    int r = it >> 7, j = it & 127;
    float acc = pr.bc1[j];
    const float* cv = pr.cov + (size_t)(row0 + r)*COVSZ;
    const float* wv = pr.Wc1 + (size_t)j*COVSZ;
    for (int k = 0; k < COVSZ; ++k) acc += cv[k]*wv[k];
    sm.p_f[r*LPF + j] = fmaxf(acc, 0.0f);
  }
  __syncthreads();
  for (int it = tid; it < 16*HID; it += NTH){
    int r = it / HID, j = it - r*HID;
    float acc = pr.bc2[j];
    const float* wv = pr.Wc2 + (size_t)j*COVH;
    for (int k = 0; k < COVH; ++k) acc += sm.p_f[r*LPF + k]*wv[k];
    sm.h_b[r*LHB + j] = f2bf(tanh_f(acc));
  }
  #pragma unroll
  for (int s = 0; s < 2; ++s){
    bool act = (s == 0) || vA1;
    int tt = s ? tA1 : tA0;
    int n = tt*16 + c;
    const float* wv = pr.Wc2 + (size_t)n*COVH;
    #pragma unroll
    for (int i = 0; i < 4; ++i){
      int r = g*4 + i;
      float acc = pr.bc2[n];
      for (int k = 0; k < COVH; ++k) acc += sm.p_f[r*LPF + k]*wv[k];
      hreg[s][i] = act ? tanh_f(acc) : 0.0f;
    }
  }
  __syncthreads();

  // r21: pm1 REPLICATED (all 32 tiles, NT=4; r17-verified expressions) —
  // removes 3 gsync + 3 copyLDS + 3 publishes per step. ph1 stays local.
  auto pm1R = [&](){
    f32x4 acc[4] = {};
    dotP<24, 4>(sm.h_b, LHB, pr.Wp1, 0, acc, c, g, lane, w);
    #pragma unroll
    for (int j = 0; j < 4; ++j){
      int n = (w + 8*j)*16 + c;
      float bb = pr.bp1[n];
      #pragma unroll
      for (int i = 0; i < 4; ++i)
        sm.u.ph1[(g*4 + i)*LPH + n] = f2bf(fmaxf(acc[j][i] + bb, 0.0f));
    }
    __syncthreads();
  };
  auto pm2R = [&](bool write_pb){
    f32x4 acc[1] = {};
    dotPB16(sm.u.ph1, LPH, pr.Wp2, acc, c, g, lane, w);
    int n = w*16 + c;
    float bb = pr.bp2[n];
    #pragma unroll
    for (int i = 0; i < 4; ++i){
      float v = acc[0][i] + bb;
      sm.p_f[(g*4 + i)*LPF + n] = v;
      if (write_pb) sm.p_b[(g*4 + i)*LPB + n] = f2bf(v);
    }
    __syncthreads();
  };

  pm1R();
  pm2R(true);

  float Xs[2], Ms[2];

  #pragma unroll 1
  for (int t = 0; t < NUM_T; ++t){
    if (tid < 16) sm.om[t & 1][tid] = pr.obs[(size_t)t*BATCH + row0 + tid];
    float Xpre[2];
    #pragma unroll
    for (int q2 = 0; q2 < 2; ++q2){
      int it = tid + q2*NTH;
      int r = it >> 6, d = it & 63;
      Xpre[q2] = pr.X[((size_t)t*BATCH + row0 + r)*DIM + d];
    }

    // ---- A1: z at owned cols; publish zh slice ----
    {
      f32x4 accz[2] = {};
      dotPG<4>(sm.p_b, LPB, pr.Wxz, tA0, tA1, vA1, accz, c, g, lane);
      dotPG<24>(sm.h_b, LHB, pr.Whz, tA0, tA1, vA1, accz, c, g, lane);
      #pragma unroll
      for (int s = 0; s < 2; ++s){
        bool act = (s == 0) || vA1;
        if (act){
          int tt = s ? tA1 : tA0;
          int n = tt*16 + c;
          float bb = pr.bxz[n];
          #pragma unroll
          for (int i = 0; i < 4; ++i){
            int r = g*4 + i;
            float z = sigm(accz[s][i] + bb);
            sm.z_b[r*LHB + n] = f2bf(z);
            exZH[(size_t)r*HID + n] = f2bf(z*hreg[s][i]);
          }
        }
      }
      gsync();
      copyLDS(sm.u.zh, LZH, exZH, HID);
    }
    // ---- A2: h ODE update at owned cols; publish h slice ----
    {
      f32x4 accn[2] = {};
      dotPG<4>(sm.p_b, LPB, pr.Wxn, tA0, tA1, vA1, accn, c, g, lane);
      dotPG<24>(sm.u.zh, LZH, pr.Whn, tA0, tA1, vA1, accn, c, g, lane);
      #pragma unroll
      for (int s = 0; s < 2; ++s){
        bool act = (s == 0) || vA1;
        if (act){
          int tt = s ? tA1 : tA0;
          int n = tt*16 + c;
          float bb = pr.bxn[n];
          #pragma unroll
          for (int i = 0; i < 4; ++i){
            int r = g*4 + i;
            float nv = tanh_f(accn[s][i] + bb);
            float z  = bf2f(sm.z_b[r*LHB + n]);
            float h  = hreg[s][i];
            h = h + DT_*(1.0f - z)*(nv - h);
            hreg[s][i] = h;
            exH[(size_t)r*HID + n] = f2bf(h);
          }
        }
      }
      gsync();
      copyLDS(sm.h_b, LHB, exH, HID);
    }

    // ---- B,C ----
    pm1R();
    pm2R(false);

    // ---- D ----
    #pragma unroll
    for (int q2 = 0; q2 < 2; ++q2){
      int it = tid + q2*NTH;
      int r = it >> 6, d = it & 63;
      size_t xoff = ((size_t)t*BATCH + row0 + r)*DIM + d;
      float Xv = Xpre[q2];
      float om = sm.om[t & 1][r] ? 1.0f : 0.0f;
      float Mv = pr.M[xoff] * om;
      Xs[q2] = Xv; Ms[q2] = Mv;
      float mean = sm.p_f[r*LPF + d];
      float var  = sm.p_f[r*LPF + 64 + d];
      float av   = fabsf(var) + VEPS;
      float inv  = rsqrtf(av);
      float errv = (Xv - mean)*inv;
      if (q == 0) loss += 0.5f*(errv*errv + __logf(av))*Mv;
      #pragma unroll
      for (int p = 0; p < PREP; ++p){
        float s = pr.bprep[d*PREP + p]
                + Xv  * pr.wprep[(d*4 + 0)*PREP + p]
                + mean* pr.wprep[(d*4 + 1)*PREP + p]
                + av  * pr.wprep[(d*4 + 2)*PREP + p]
                + errv* pr.wprep[(d*4 + 3)*PREP + p];
        sm.u.gi[r*LGI + d*PREP + p] = f2bf(fmaxf(s, 0.0f)*Mv);
      }
    }
    __syncthreads();

    // ---- E: GRUCell jump at owned cols; publish h slice ----
    {
      float hn_buf[2][4];
      #pragma unroll 1
      for (int s = 0; s < 2; ++s){
        bool act = (s == 0) || vA1;
        int ht = s ? tA1 : tA0;
        int n = ht*16 + c;
        f32x4 ai[3] = {};
        dot3PG<20>(sm.u.gi, LGI, pr.Wih, ht, act, ai, c, g, lane);
        f32x4 ah[3] = {};
        dot3PG<24>(sm.h_b, LHB, pr.Whh, ht, act, ah, c, g, lane);
        #pragma unroll
        for (int i = 0; i < 4; ++i){
          float ir = ai[0][i] + pr.bih[n];
          float iz = ai[1][i] + pr.bih[HID + n];
          float in = ai[2][i] + pr.bih[2*HID + n];
          float hr = ah[0][i] + pr.bhh[n];
          float hz = ah[1][i] + pr.bhh[HID + n];
          float hn = ah[2][i] + pr.bhh[2*HID + n];
          float rr  = sigm(ir + hr);
          float zz  = sigm(iz + hz);
          float nn  = tanh_f(in + rr*hn);
          hn_buf[s][i] = (1.0f - zz)*nn + zz*hreg[s][i];
        }
      }
      #pragma unroll
      for (int s = 0; s < 2; ++s){
        bool act = (s == 0) || vA1;
        if (act){
          int tt = s ? tA1 : tA0;
          int n = tt*16 + c;
          #pragma unroll
          for (int i = 0; i < 4; ++i){
            int r = g*4 + i;
            if (sm.om[t & 1][r]) hreg[s][i] = hn_buf[s][i];
            exH[(size_t)r*HID + n] = f2bf(hreg[s][i]);
          }
        }
      }
      gsync();
      copyLDS(sm.h_b, LHB, exH, HID);
    }

    // ---- F,G ----
    pm1R();
    pm2R(true);

    // ---- H ----
    if (q == 0){
      #pragma unroll
      for (int q2 = 0; q2 < 2; ++q2){
        int it = tid + q2*NTH;
        int r = it >> 6, d = it & 63;
        float mean = sm.p_f[r*LPF + d];
        float var  = sm.p_f[r*LPF + 64 + d];
        float av   = fabsf(var) + VEPS;
        float inv  = rsqrtf(av);
        float errv = (Xs[q2] - mean)*inv;
        loss += 0.5f*(errv*errv + __logf(av))*Ms[q2];
      }
    }
  }

  __syncthreads();
  #pragma unroll
  for (int s = 0; s < 2; ++s){
    bool act = (s == 0) || vA1;
    if (act){
      int tt = s ? tA1 : tA0;
      int n = tt*16 + c;
      #pragma unroll
      for (int i = 0; i < 4; ++i){
        int r = g*4 + i;
        pr.out_h[(size_t)(row0 + r)*HID + n] = hreg[s][i];
      }
    }
  }
  #pragma unroll
  for (int off = 32; off >= 1; off >>= 1) loss += __shfl_down(loss, off);
  if (lane == 0) sm.red[w] = loss;
  __syncthreads();
  if (tid == 0 && q == 0){
    float ssum = 0.0f;
    for (int i = 0; i < NWAVE; ++i) ssum += sm.red[i];
    pr.partials[G] = ssum;
  }
}

__global__ void k_swz(const float* __restrict__ s, u16* __restrict__ d, int N, int K){
  int i = blockIdx.x*blockDim.x + threadIdx.x;
  if (i >= N*K) return;
  int e    = i & 7;
  int lane = (i >> 3) & 63;
  int rest = i >> 9;
  int ks = K >> 5;
  int k = rest % ks, t = rest / ks;
  int cc = lane & 15, gg = lane >> 4;
  d[i] = f2bf(s[(size_t)(t*16 + cc)*K + (k*32 + gg*8 + e)]);
}

__global__ void k_final(const float* __restrict__ partials, float* __restrict__ out_loss){
  float v = (threadIdx.x < GROUPS) ? partials[threadIdx.x] : 0.0f;
  #pragma unroll
  for (int off = 32; off >= 1; off >>= 1) v += __shfl_down(v, off);
  if (threadIdx.x == 0) out_loss[0] = v;
}

extern "C" void kernel_launch(void* const* d_in, const int* in_sizes, int n_in,
                              void* d_out, int out_size, void* d_ws, size_t ws_size,
                              hipStream_t stream)
{
  const float* X   = (const float*)d_in[0];
  const float* M   = (const float*)d_in[1];
  const int*   obs = (const int*)  d_in[2];
  const float* cov = (const float*)d_in[3];
  const float* Wxz = (const float*)d_in[4];
  const float* bxz = (const float*)d_in[5];
  const float* Wxn = (const float*)d_in[6];
  const float* bxn = (const float*)d_in[7];
  const float* Whz = (const float*)d_in[8];
  const float* Whn = (const float*)d_in[9];
  const float* Wp1 = (const float*)d_in[10];
  const float* bp1 = (const float*)d_in[11];
  const float* Wp2 = (const float*)d_in[12];
  const float* bp2 = (const float*)d_in[13];
  const float* Wc1 = (const float*)d_in[14];
  const float* bc1 = (const float*)d_in[15];
  const float* Wc2 = (const float*)d_in[16];
  const float* bc2 = (const float*)d_in[17];
  const float* Wih = (const float*)d_in[18];
  const float* Whh = (const float*)d_in[19];
  const float* bih = (const float*)d_in[20];
  const float* bhh = (const float*)d_in[21];
  const float* wprep = (const float*)d_in[22];
  const float* bprep = (const float*)d_in[23];

  u16* w = (u16*)d_ws;
  u16* wXZ = w + 0;
  u16* wXN = w + 98304;
  u16* wHZ = w + 196608;
  u16* wHN = w + 786432;
  u16* wP1 = w + 1376256;
  u16* wP2 = w + 1769472;
  u16* wIH = w + 1835008;
  u16* wHH = w + 3309568;
  float*    partials = (float*)((char*)d_ws + 10158080);
  unsigned* cnt      = (unsigned*)((char*)d_ws + 10158336);
  u16*      exch     = (u16*)((char*)d_ws + 10162432);

  struct CV { const float* s; u16* d; int N; int K; } cvs[8] = {
    {Wxz, wXZ, 768, 128}, {Wxn, wXN, 768, 128}, {Whz, wHZ, 768, 768}, {Whn, wHN, 768, 768},
    {Wp1, wP1, 512, 768}, {Wp2, wP2, 128, 512}, {Wih, wIH, 2304, 640}, {Whh, wHH, 2304, 768},
  };
  for (int i = 0; i < 8; ++i){
    int n = cvs[i].N * cvs[i].K;
    k_swz<<<(n + 255)/256, 256, 0, stream>>>(cvs[i].s, cvs[i].d, cvs[i].N, cvs[i].K);
  }
  hipMemsetAsync(cnt, 0, 4096, stream);

  Params pr { X, M, obs, cov, bxz, bxn, bp1, bp2, bc1, bc2, bih, bhh, wprep, bprep,
              Wc1, Wc2, wXZ, wXN, wHZ, wHN, wP1, wP2, wIH, wHH,
              (float*)d_out, partials, exch, cnt };
  nnfo_main<<<NWG, NTH, 0, stream>>>(pr);
  k_final<<<1, 64, 0, stream>>>(partials, (float*)d_out + (size_t)BATCH*HID);
}